// Round 6
// baseline (909.987 us; speedup 1.0000x reference)
//
#include <hip/hip_runtime.h>

#define N_NODES 100000
#define N_EDGES 1000000
#define D_FEAT  6
#define HIDDEN  300
#define HID_P   320          // padded hidden (multiple of 32)
#define MSG     100
#define OUTC    200          // 2*MSG
#define OUTC_P  208
#define MT      64           // edges per block
#define NT_H    (HID_P/16)   // 20 feature tiles for hidden layers
#define NT_M    13           // 13 feature tiles for messages (tile 12 partial)
#define KS_H    (HID_P/32)   // 10 k-steps of 32
#define LOG2E   1.44269504f
#define LN2     0.69314718f

typedef __bf16 bf16_t;
typedef __bf16 bf16x8 __attribute__((ext_vector_type(8)));
typedef __bf16 bf16x4 __attribute__((ext_vector_type(4)));
typedef float  floatx4 __attribute__((ext_vector_type(4)));

// ---------------- prep (weight pack) + base MAE loss, merged --------------------
// B-frag order pack (doubles as A-frag order under operand swap — same index map):
// chunk of 512 el = one (ft,ks) fragment: el = ((ft*KS+ks)*64+lane)*8+j,
// element = W[k][n], n = ft*16+(lane&15), k = ks*32+(lane>>4)*8+j, zero-padded.
// W3 logvar columns (n >= MSG) are pre-scaled by log2(e): the GEMM then yields
// lv*log2e, so KL's exp is a bare v_exp_f32 (exp2) and lv = acc*ln2.
#define PREP_BLOCKS 700
#define LOSS_BLOCKS 200
__global__ void prep_kernel(const float* __restrict__ W1, const float* __restrict__ W2,
                            const float* __restrict__ W3, bf16_t* __restrict__ W1P,
                            bf16_t* __restrict__ W2P, bf16_t* __restrict__ W3P,
                            const float* __restrict__ y, const float* __restrict__ t,
                            float* __restrict__ out) {
    if (blockIdx.x >= PREP_BLOCKS) {
        float s = 0.f;
        for (int i = (blockIdx.x - PREP_BLOCKS) * blockDim.x + threadIdx.x;
             i < N_NODES * 2; i += LOSS_BLOCKS * blockDim.x)
            s += fabsf(y[i] - t[i]);
        #pragma unroll
        for (int off = 32; off; off >>= 1) s += __shfl_down(s, off);
        __shared__ float red[4];
        if ((threadIdx.x & 63) == 0) red[threadIdx.x >> 6] = s;
        __syncthreads();
        if (threadIdx.x == 0)
            atomicAdd(out, (red[0] + red[1] + red[2] + red[3]) * (1.0f / N_NODES));
        return;
    }
    const int n1 = NT_H * 512;
    const int n2 = NT_H * KS_H * 512;
    const int n3 = NT_M * KS_H * 512;
    const int total = n1 + n2 + n3;
    for (int id = blockIdx.x * blockDim.x + threadIdx.x; id < total;
         id += PREP_BLOCKS * blockDim.x) {
        if (id < n1) {
            int nt = id >> 9, rem = id & 511, lane = rem >> 3, j = rem & 7;
            int n = nt * 16 + (lane & 15), k = (lane >> 4) * 8 + j;
            float v = (n < HIDDEN && k < 2 * D_FEAT) ? W1[k * HIDDEN + n] : 0.f;
            W1P[id] = (bf16_t)v;
        } else if (id < n1 + n2) {
            int r = id - n1;
            int chunk = r >> 9, rem = r & 511, lane = rem >> 3, j = rem & 7;
            int ks = chunk % KS_H, nt = chunk / KS_H;
            int n = nt * 16 + (lane & 15), k = ks * 32 + (lane >> 4) * 8 + j;
            float v = (n < HIDDEN && k < HIDDEN) ? W2[k * HIDDEN + n] : 0.f;
            W2P[r] = (bf16_t)v;
        } else {
            int r = id - n1 - n2;
            int chunk = r >> 9, rem = r & 511, lane = rem >> 3, j = rem & 7;
            int ks = chunk % KS_H, nt = chunk / KS_H;
            int n = nt * 16 + (lane & 15), k = ks * 32 + (lane >> 4) * 8 + j;
            float v = (n < OUTC && k < HIDDEN) ? W3[k * OUTC + n] : 0.f;
            if (n >= MSG) v *= LOG2E;            // logvar columns pre-scaled
            W3P[r] = (bf16_t)v;
        }
    }
}

static __device__ __forceinline__ floatx4 mfma16(bf16x8 a, bf16x8 b, floatx4 c) {
    return __builtin_amdgcn_mfma_f32_16x16x32_bf16(a, b, c, 0, 0, 0);
}

// GEMM phase, 4-wave decomposition: wave w owns nts {5w..5w+4} x all 4 edge
// tiles = 20 jobs/wave, exactly balanced. BIAS RIDES IN C. T5: setprio(1)
// around each k-step's MFMA cluster — 3 independent blocks/CU are at
// different phases, so MFMA-dense waves win issue slots over epilogue waves.
template<int KSN, int SE>
__device__ __forceinline__ void gemm5x4(
    const bf16_t* __restrict__ Wbase0,     // W pack + (5w)*KSN*512
    const bf16_t* __restrict__ Hsrc, int lane,
    const floatx4 (&binit)[5], floatx4 (&acc)[5][4]) {
    #pragma unroll
    for (int i = 0; i < 5; i++)
        #pragma unroll
        for (int e = 0; e < 4; e++) acc[i][e] = binit[i];
    const bf16_t* Wb = Wbase0 + lane * 8;
    const bf16_t* Hb = Hsrc + lane * 8;
    #pragma unroll 2
    for (int ks = 0; ks < KSN; ks++) {
        bf16x8 hb0 = *(const bf16x8*)(Hb + ks * 512);
        bf16x8 hb1 = *(const bf16x8*)(Hb + ks * 512 + SE);
        bf16x8 hb2 = *(const bf16x8*)(Hb + ks * 512 + 2 * SE);
        bf16x8 hb3 = *(const bf16x8*)(Hb + ks * 512 + 3 * SE);
        __builtin_amdgcn_s_setprio(1);
        #pragma unroll
        for (int i = 0; i < 5; i++) {
            bf16x8 wf = *(const bf16x8*)(Wb + i * (KSN * 512) + ks * 512);
            acc[i][0] = mfma16(wf, hb0, acc[i][0]);
            acc[i][1] = mfma16(wf, hb1, acc[i][1]);
            acc[i][2] = mfma16(wf, hb2, acc[i][2]);
            acc[i][3] = mfma16(wf, hb3, acc[i][3]);
        }
        __builtin_amdgcn_s_setprio(0);
    }
}

// Epilogue: relu + pack to bf16 (bias already in C), write in B-frag order.
// C/D layout: n(edge)=lane&15, m(feat)=(lane>>4)*4+reg  (verified, absmax 0).
__device__ __forceinline__ void epi5(
    bf16_t* __restrict__ Hf, int w, int q, int l16, const floatx4 (&acc)[5][4]) {
    #pragma unroll
    for (int i = 0; i < 5; i++) {
        int n0 = (5 * w + i) * 16 + 4 * q;
        int ks = n0 >> 5, lp = l16 + 16 * ((n0 >> 3) & 3), j0 = n0 & 7;
        #pragma unroll
        for (int e = 0; e < 4; e++) {
            bf16x4 pk;
            #pragma unroll
            for (int r = 0; r < 4; r++)
                pk[r] = (bf16_t)fmaxf(acc[i][e][r], 0.f);
            *(bf16x4*)&Hf[((e * KS_H + ks) * 64 + lp) * 8 + j0] = pk;
        }
    }
}

// ---------------- fused edge MLP + KL ------------------------------------------
// OPERAND SWAP: D = mfma(A=W_frag, B=H_frag) -> D rows = features, cols = edges.
// H lives in LDS in exact B-fragment order Hf[e][ks][lane][8]; LDS = 40 KB.
// GEMM1's B-fragments are built DIRECTLY from global x/ei (no LDS staging, no
// gather barrier): B-frag (lane,j) = e[edge=et*16+l16][feat=q*8+j]; only quads
// 0,1 carry data (feats 0..11), quads 2,3 are the K-padding zeros.
// launch_bounds(256,3): (256,4)'s 128-reg cap spilled the 80-reg accumulator
// (R5: VGPR 64, WRITE_SIZE 4x, 2.4x slowdown) and 4 blocks/CU never
// materialized anyway (occupancy stayed ~36% at LDS=40960).
__global__ __launch_bounds__(256, 3) void mlp_kernel(
    const float* __restrict__ x, const int* __restrict__ ei,
    const bf16_t* __restrict__ W1P, const bf16_t* __restrict__ W2P,
    const bf16_t* __restrict__ W3P,
    const float* __restrict__ b1, const float* __restrict__ b2,
    const float* __restrict__ b3, float* __restrict__ out) {
    __shared__ __align__(16) bf16_t Hf[4 * KS_H * 64 * 8];    // 40 KB

    const int tid  = threadIdx.x;
    const int w    = tid >> 6, lane = tid & 63;
    const int q    = lane >> 4, l16 = lane & 15;
    const long e0 = (long)blockIdx.x * MT;

    // ---- preload W1 fragments + b1 C-init vectors ----
    bf16x8 wf1[5];
    floatx4 bv1[5];
    #pragma unroll
    for (int i = 0; i < 5; i++) {
        wf1[i] = *(const bf16x8*)&W1P[((5 * w + i) * 64 + lane) * 8];
        int n0 = (5 * w + i) * 16 + 4 * q;
        bv1[i] = (n0 < HIDDEN) ? *(const floatx4*)&b1[n0] : (floatx4){0.f, 0.f, 0.f, 0.f};
    }

    // ---- GEMM1 B-fragments direct from global ----
    bf16x8 hbg[4];
    #pragma unroll
    for (int et = 0; et < 4; et++) {
        bf16x8 v = {};
        long g = e0 + et * 16 + l16;
        if (q == 0) {                          // feats 0..5 = src, 6..7 = dst[0..1]
            int si = ei[g], di = ei[N_EDGES + g];
            const float2* xs = (const float2*)(x + (long)si * D_FEAT);
            const float2* xd = (const float2*)(x + (long)di * D_FEAT);
            float2 a0 = xs[0], a1 = xs[1], a2 = xs[2], c0 = xd[0];
            v[0] = (bf16_t)a0.x; v[1] = (bf16_t)a0.y;
            v[2] = (bf16_t)a1.x; v[3] = (bf16_t)a1.y;
            v[4] = (bf16_t)a2.x; v[5] = (bf16_t)a2.y;
            v[6] = (bf16_t)c0.x; v[7] = (bf16_t)c0.y;
        } else if (q == 1) {                   // feats 8..11 = dst[2..5], 12..15 = 0
            int di = ei[N_EDGES + g];
            const float2* xd = (const float2*)(x + (long)di * D_FEAT);
            float2 c1 = xd[1], c2 = xd[2];
            v[0] = (bf16_t)c1.x; v[1] = (bf16_t)c1.y;
            v[2] = (bf16_t)c2.x; v[3] = (bf16_t)c2.y;
        }
        hbg[et] = v;                           // quads 2,3: zeros (K padding)
    }

    floatx4 acc[5][4];

    // ---- GEMM1: h1 = relu(e @ W1 + b1), K=32 (one step) ----
    #pragma unroll
    for (int i = 0; i < 5; i++) {
        acc[i][0] = mfma16(wf1[i], hbg[0], bv1[i]);
        acc[i][1] = mfma16(wf1[i], hbg[1], bv1[i]);
        acc[i][2] = mfma16(wf1[i], hbg[2], bv1[i]);
        acc[i][3] = mfma16(wf1[i], hbg[3], bv1[i]);
    }
    epi5(Hf, w, q, l16, acc);
    // preload b2 C-init here (issues before barrier region, consumed at GEMM2)
    floatx4 bv2[5];
    #pragma unroll
    for (int i = 0; i < 5; i++) {
        int n0 = (5 * w + i) * 16 + 4 * q;
        bv2[i] = (n0 < HIDDEN) ? *(const floatx4*)&b2[n0] : (floatx4){0.f, 0.f, 0.f, 0.f};
    }
    __syncthreads();

    // ---- GEMM2: h2 = relu(h1 @ W2 + b2), K=320, bias in C ----
    gemm5x4<KS_H, KS_H * 512>(W2P + (5 * w) * (KS_H * 512), Hf, lane, bv2, acc);
    __syncthreads();   // all Hf(h1) reads done before overwrite
    epi5(Hf, w, q, l16, acc);
    __syncthreads();

    // ---- GEMM3: messages = h2 @ W3(+log2e-scaled lv) + b3 (bias in C), KL ----
    floatx4 a3[3][4], aq;
    const int n0q = 192 + 4 * q;                  // tile 12, logvar only
    {
        #pragma unroll
        for (int t = 0; t < 3; t++) {
            int n0 = (3 * w + t) * 16 + 4 * q;    // 0..191, always valid
            floatx4 bv = *(const floatx4*)&b3[n0];
            if (n0 >= MSG) bv = bv * LOG2E;       // logvar bias in log2e units
            #pragma unroll
            for (int e = 0; e < 4; e++) a3[t][e] = bv;
        }
        aq = (n0q < OUTC) ? *(const floatx4*)&b3[n0q] * LOG2E
                          : (floatx4){0.f, 0.f, 0.f, 0.f};
    }
    {
        const bf16_t* W3b = W3P + (3 * w) * (KS_H * 512) + lane * 8;
        const bf16_t* Wqb = W3P + 12 * (KS_H * 512) + lane * 8;
        const bf16_t* Hb  = Hf + lane * 8;
        const bf16_t* Hq  = Hf + w * (KS_H * 512) + lane * 8;   // et = w fragment
        #pragma unroll 2
        for (int ks = 0; ks < KS_H; ks++) {
            bf16x8 hb0 = *(const bf16x8*)(Hb + ks * 512);
            bf16x8 hb1 = *(const bf16x8*)(Hb + ks * 512 + KS_H * 512);
            bf16x8 hb2 = *(const bf16x8*)(Hb + ks * 512 + 2 * KS_H * 512);
            bf16x8 hb3 = *(const bf16x8*)(Hb + ks * 512 + 3 * KS_H * 512);
            bf16x8 wq = *(const bf16x8*)(Wqb + ks * 512);
            bf16x8 hq = *(const bf16x8*)(Hq + ks * 512);
            __builtin_amdgcn_s_setprio(1);
            #pragma unroll
            for (int t = 0; t < 3; t++) {
                bf16x8 wf = *(const bf16x8*)(W3b + t * (KS_H * 512) + ks * 512);
                a3[t][0] = mfma16(wf, hb0, a3[t][0]);
                a3[t][1] = mfma16(wf, hb1, a3[t][1]);
                a3[t][2] = mfma16(wf, hb2, a3[t][2]);
                a3[t][3] = mfma16(wf, hb3, a3[t][3]);
            }
            aq = mfma16(wq, hq, aq);
            __builtin_amdgcn_s_setprio(0);
        }
    }
    // KL: mu -> sm += v*v; logvar (log2e units) -> se += exp2(v'), sv' += v',
    // cnt += group size. total = 0.5*(sm + se - ln2*sv' - cnt).
    float sm = 0.f, se = 0.f, svp = 0.f, cnt = 0.f;
    #pragma unroll
    for (int t = 0; t < 3; t++) {
        int n0 = (3 * w + t) * 16 + 4 * q;
        if (n0 < MSG) {                           // 4-runs never straddle 100
            #pragma unroll
            for (int e = 0; e < 4; e++)
                #pragma unroll
                for (int r = 0; r < 4; r++) {
                    float v = a3[t][e][r];
                    sm += v * v;
                }
        } else {
            #pragma unroll
            for (int e = 0; e < 4; e++)
                #pragma unroll
                for (int r = 0; r < 4; r++) {
                    float v = a3[t][e][r];
                    se += __builtin_exp2f(v);
                    svp += v;
                }
            cnt += 16.f;
        }
    }
    if (n0q < OUTC) {
        #pragma unroll
        for (int r = 0; r < 4; r++) {
            float v = aq[r];
            se += __builtin_exp2f(v);
            svp += v;
        }
        cnt += 4.f;
    }
    float s = sm + se - svp * LN2 - cnt;
    #pragma unroll
    for (int off = 32; off; off >>= 1) s += __shfl_down(s, off);
    if (lane == 0)
        atomicAdd(out, s * (0.5f / N_EDGES));     // per-wave atomic (4/block)
}

extern "C" void kernel_launch(void* const* d_in, const int* in_sizes, int n_in,
                              void* d_out, int out_size, void* d_ws, size_t ws_size,
                              hipStream_t stream) {
    const float* x      = (const float*)d_in[0];
    const int*   ei     = (const int*)d_in[1];
    const float* y      = (const float*)d_in[2];
    const float* target = (const float*)d_in[3];
    const float* W1     = (const float*)d_in[4];
    const float* b1     = (const float*)d_in[5];
    const float* W2     = (const float*)d_in[6];
    const float* b2     = (const float*)d_in[7];
    const float* W3     = (const float*)d_in[8];
    const float* b3     = (const float*)d_in[9];
    float* out = (float*)d_out;

    bf16_t* W1P = (bf16_t*)d_ws;
    bf16_t* W2P = W1P + NT_H * 512;
    bf16_t* W3P = W2P + NT_H * KS_H * 512;

    hipMemsetAsync(d_out, 0, sizeof(float), stream);
    prep_kernel<<<PREP_BLOCKS + LOSS_BLOCKS, 256, 0, stream>>>(
        W1, W2, W3, W1P, W2P, W3P, y, target, out);
    mlp_kernel<<<N_EDGES / MT, 256, 0, stream>>>(x, ei, W1P, W2P, W3P, b1, b2, b3, out);
}

// Round 7
// 459.759 us; speedup vs baseline: 1.9793x; 1.9793x over previous
//
#include <hip/hip_runtime.h>

#define N_NODES 100000
#define N_EDGES 1000000
#define D_FEAT  6
#define HIDDEN  300
#define HID_P   320          // padded hidden (multiple of 32)
#define MSG     100
#define OUTC    200          // 2*MSG
#define OUTC_P  208
#define MT      64           // edges per block
#define NT_H    (HID_P/16)   // 20 feature tiles for hidden layers
#define NT_M    13           // 13 feature tiles for messages (tile 12 partial)
#define KS_H    (HID_P/32)   // 10 k-steps of 32
#define NPART   (N_EDGES/MT) // 15625 per-block partials
#define LOG2E   1.44269504f
#define LN2     0.69314718f

typedef __bf16 bf16_t;
typedef __bf16 bf16x8 __attribute__((ext_vector_type(8)));
typedef __bf16 bf16x4 __attribute__((ext_vector_type(4)));
typedef float  floatx4 __attribute__((ext_vector_type(4)));

// ---------------- prep (weight pack) + base MAE loss, merged --------------------
// B-frag order pack: chunk of 512 el = one (ft,ks) fragment:
// el = ((ft*KS+ks)*64+lane)*8+j, element = W[k][n], n = ft*16+(lane&15),
// k = ks*32+(lane>>4)*8+j, zero-padded. W3 logvar cols (n>=MSG) pre-scaled by
// log2(e) so KL's exp is a bare v_exp_f32 (exp2).
#define PREP_BLOCKS 700
#define LOSS_BLOCKS 200
__global__ void prep_kernel(const float* __restrict__ W1, const float* __restrict__ W2,
                            const float* __restrict__ W3, bf16_t* __restrict__ W1P,
                            bf16_t* __restrict__ W2P, bf16_t* __restrict__ W3P,
                            const float* __restrict__ y, const float* __restrict__ t,
                            float* __restrict__ out) {
    if (blockIdx.x >= PREP_BLOCKS) {
        float s = 0.f;
        for (int i = (blockIdx.x - PREP_BLOCKS) * blockDim.x + threadIdx.x;
             i < N_NODES * 2; i += LOSS_BLOCKS * blockDim.x)
            s += fabsf(y[i] - t[i]);
        #pragma unroll
        for (int off = 32; off; off >>= 1) s += __shfl_down(s, off);
        __shared__ float red[4];
        if ((threadIdx.x & 63) == 0) red[threadIdx.x >> 6] = s;
        __syncthreads();
        if (threadIdx.x == 0)
            atomicAdd(out, (red[0] + red[1] + red[2] + red[3]) * (1.0f / N_NODES));
        return;
    }
    const int n1 = NT_H * 512;
    const int n2 = NT_H * KS_H * 512;
    const int n3 = NT_M * KS_H * 512;
    const int total = n1 + n2 + n3;
    for (int id = blockIdx.x * blockDim.x + threadIdx.x; id < total;
         id += PREP_BLOCKS * blockDim.x) {
        if (id < n1) {
            int nt = id >> 9, rem = id & 511, lane = rem >> 3, j = rem & 7;
            int n = nt * 16 + (lane & 15), k = (lane >> 4) * 8 + j;
            float v = (n < HIDDEN && k < 2 * D_FEAT) ? W1[k * HIDDEN + n] : 0.f;
            W1P[id] = (bf16_t)v;
        } else if (id < n1 + n2) {
            int r = id - n1;
            int chunk = r >> 9, rem = r & 511, lane = rem >> 3, j = rem & 7;
            int ks = chunk % KS_H, nt = chunk / KS_H;
            int n = nt * 16 + (lane & 15), k = ks * 32 + (lane >> 4) * 8 + j;
            float v = (n < HIDDEN && k < HIDDEN) ? W2[k * HIDDEN + n] : 0.f;
            W2P[r] = (bf16_t)v;
        } else {
            int r = id - n1 - n2;
            int chunk = r >> 9, rem = r & 511, lane = rem >> 3, j = rem & 7;
            int ks = chunk % KS_H, nt = chunk / KS_H;
            int n = nt * 16 + (lane & 15), k = ks * 32 + (lane >> 4) * 8 + j;
            float v = (n < OUTC && k < HIDDEN) ? W3[k * OUTC + n] : 0.f;
            if (n >= MSG) v *= LOG2E;            // logvar columns pre-scaled
            W3P[r] = (bf16_t)v;
        }
    }
}

// ---------------- final reduce: sum per-block KL partials into out -------------
#define RED_BLOCKS 64
__global__ void reduce_kernel(const float* __restrict__ part, float* __restrict__ out) {
    float s = 0.f;
    for (int i = blockIdx.x * blockDim.x + threadIdx.x; i < NPART;
         i += RED_BLOCKS * blockDim.x)
        s += part[i];
    #pragma unroll
    for (int off = 32; off; off >>= 1) s += __shfl_down(s, off);
    __shared__ float red[4];
    if ((threadIdx.x & 63) == 0) red[threadIdx.x >> 6] = s;
    __syncthreads();
    if (threadIdx.x == 0)
        atomicAdd(out, (red[0] + red[1] + red[2] + red[3]) * (0.5f / N_EDGES));
}

static __device__ __forceinline__ floatx4 mfma16(bf16x8 a, bf16x8 b, floatx4 c) {
    return __builtin_amdgcn_mfma_f32_16x16x32_bf16(a, b, c, 0, 0, 0);
}

// GEMM phase, 4-wave decomposition: wave w owns nts {5w..5w+4} x all 4 edge
// tiles = 20 jobs/wave, exactly balanced. BIAS RIDES IN C. T5 setprio around
// the MFMA cluster (3 independent blocks/CU at different phases).
template<int KSN, int SE>
__device__ __forceinline__ void gemm5x4(
    const bf16_t* __restrict__ Wbase0,     // W pack + (5w)*KSN*512
    const bf16_t* __restrict__ Hsrc, int lane,
    const floatx4 (&binit)[5], floatx4 (&acc)[5][4]) {
    #pragma unroll
    for (int i = 0; i < 5; i++)
        #pragma unroll
        for (int e = 0; e < 4; e++) acc[i][e] = binit[i];
    const bf16_t* Wb = Wbase0 + lane * 8;
    const bf16_t* Hb = Hsrc + lane * 8;
    #pragma unroll 2
    for (int ks = 0; ks < KSN; ks++) {
        bf16x8 hb0 = *(const bf16x8*)(Hb + ks * 512);
        bf16x8 hb1 = *(const bf16x8*)(Hb + ks * 512 + SE);
        bf16x8 hb2 = *(const bf16x8*)(Hb + ks * 512 + 2 * SE);
        bf16x8 hb3 = *(const bf16x8*)(Hb + ks * 512 + 3 * SE);
        __builtin_amdgcn_s_setprio(1);
        #pragma unroll
        for (int i = 0; i < 5; i++) {
            bf16x8 wf = *(const bf16x8*)(Wb + i * (KSN * 512) + ks * 512);
            acc[i][0] = mfma16(wf, hb0, acc[i][0]);
            acc[i][1] = mfma16(wf, hb1, acc[i][1]);
            acc[i][2] = mfma16(wf, hb2, acc[i][2]);
            acc[i][3] = mfma16(wf, hb3, acc[i][3]);
        }
        __builtin_amdgcn_s_setprio(0);
    }
}

// Epilogue: relu + pack to bf16 (bias already in C), write in B-frag order.
// C/D layout: n(edge)=lane&15, m(feat)=(lane>>4)*4+reg  (verified, absmax 0).
__device__ __forceinline__ void epi5(
    bf16_t* __restrict__ Hf, int w, int q, int l16, const floatx4 (&acc)[5][4]) {
    #pragma unroll
    for (int i = 0; i < 5; i++) {
        int n0 = (5 * w + i) * 16 + 4 * q;
        int ks = n0 >> 5, lp = l16 + 16 * ((n0 >> 3) & 3), j0 = n0 & 7;
        #pragma unroll
        for (int e = 0; e < 4; e++) {
            bf16x4 pk;
            #pragma unroll
            for (int r = 0; r < 4; r++)
                pk[r] = (bf16_t)fmaxf(acc[i][e][r], 0.f);
            *(bf16x4*)&Hf[((e * KS_H + ks) * 64 + lp) * 8 + j0] = pk;
        }
    }
}

// ---------------- fused edge MLP + KL ------------------------------------------
// OPERAND SWAP: D = mfma(A=W_frag, B=H_frag) -> D rows = features, cols = edges.
// H in LDS in exact B-fragment order Hf[e][ks][lane][8]; GEMM1 B-frags built
// directly from global x/ei. NO ATOMICS HERE: R5/R6 showed 4 same-address
// atomics/block serialize at the coherence point (~13ns each; 62.5k -> 810us,
// WRITE_SIZE = 32B x atomic count). Per-block partial -> plain store -> reduce.
__global__ __launch_bounds__(256, 3) void mlp_kernel(
    const float* __restrict__ x, const int* __restrict__ ei,
    const bf16_t* __restrict__ W1P, const bf16_t* __restrict__ W2P,
    const bf16_t* __restrict__ W3P,
    const float* __restrict__ b1, const float* __restrict__ b2,
    const float* __restrict__ b3, float* __restrict__ part) {
    __shared__ __align__(16) bf16_t Hf[4 * KS_H * 64 * 8];    // 40 KB
    __shared__ float red[4];

    const int tid  = threadIdx.x;
    const int w    = tid >> 6, lane = tid & 63;
    const int q    = lane >> 4, l16 = lane & 15;
    const long e0 = (long)blockIdx.x * MT;

    // ---- preload W1 fragments + b1 C-init vectors ----
    bf16x8 wf1[5];
    floatx4 bv1[5];
    #pragma unroll
    for (int i = 0; i < 5; i++) {
        wf1[i] = *(const bf16x8*)&W1P[((5 * w + i) * 64 + lane) * 8];
        int n0 = (5 * w + i) * 16 + 4 * q;
        bv1[i] = (n0 < HIDDEN) ? *(const floatx4*)&b1[n0] : (floatx4){0.f, 0.f, 0.f, 0.f};
    }

    // ---- GEMM1 B-fragments direct from global ----
    bf16x8 hbg[4];
    #pragma unroll
    for (int et = 0; et < 4; et++) {
        bf16x8 v = {};
        long g = e0 + et * 16 + l16;
        if (q == 0) {                          // feats 0..5 = src, 6..7 = dst[0..1]
            int si = ei[g], di = ei[N_EDGES + g];
            const float2* xs = (const float2*)(x + (long)si * D_FEAT);
            const float2* xd = (const float2*)(x + (long)di * D_FEAT);
            float2 a0 = xs[0], a1 = xs[1], a2 = xs[2], c0 = xd[0];
            v[0] = (bf16_t)a0.x; v[1] = (bf16_t)a0.y;
            v[2] = (bf16_t)a1.x; v[3] = (bf16_t)a1.y;
            v[4] = (bf16_t)a2.x; v[5] = (bf16_t)a2.y;
            v[6] = (bf16_t)c0.x; v[7] = (bf16_t)c0.y;
        } else if (q == 1) {                   // feats 8..11 = dst[2..5], 12..15 = 0
            int di = ei[N_EDGES + g];
            const float2* xd = (const float2*)(x + (long)di * D_FEAT);
            float2 c1 = xd[1], c2 = xd[2];
            v[0] = (bf16_t)c1.x; v[1] = (bf16_t)c1.y;
            v[2] = (bf16_t)c2.x; v[3] = (bf16_t)c2.y;
        }
        hbg[et] = v;                           // quads 2,3: zeros (K padding)
    }

    floatx4 acc[5][4];

    // ---- GEMM1: h1 = relu(e @ W1 + b1), K=32 (one step) ----
    #pragma unroll
    for (int i = 0; i < 5; i++) {
        acc[i][0] = mfma16(wf1[i], hbg[0], bv1[i]);
        acc[i][1] = mfma16(wf1[i], hbg[1], bv1[i]);
        acc[i][2] = mfma16(wf1[i], hbg[2], bv1[i]);
        acc[i][3] = mfma16(wf1[i], hbg[3], bv1[i]);
    }
    epi5(Hf, w, q, l16, acc);
    // preload b2 C-init here (issues before barrier region, consumed at GEMM2)
    floatx4 bv2[5];
    #pragma unroll
    for (int i = 0; i < 5; i++) {
        int n0 = (5 * w + i) * 16 + 4 * q;
        bv2[i] = (n0 < HIDDEN) ? *(const floatx4*)&b2[n0] : (floatx4){0.f, 0.f, 0.f, 0.f};
    }
    __syncthreads();

    // ---- GEMM2: h2 = relu(h1 @ W2 + b2), K=320, bias in C ----
    gemm5x4<KS_H, KS_H * 512>(W2P + (5 * w) * (KS_H * 512), Hf, lane, bv2, acc);
    __syncthreads();   // all Hf(h1) reads done before overwrite
    epi5(Hf, w, q, l16, acc);
    __syncthreads();

    // ---- GEMM3: messages = h2 @ W3(+log2e-scaled lv) + b3 (bias in C), KL ----
    floatx4 a3[3][4], aq;
    const int n0q = 192 + 4 * q;                  // tile 12, logvar only
    {
        #pragma unroll
        for (int t = 0; t < 3; t++) {
            int n0 = (3 * w + t) * 16 + 4 * q;    // 0..191, always valid
            floatx4 bv = *(const floatx4*)&b3[n0];
            if (n0 >= MSG) bv = bv * LOG2E;       // logvar bias in log2e units
            #pragma unroll
            for (int e = 0; e < 4; e++) a3[t][e] = bv;
        }
        aq = (n0q < OUTC) ? *(const floatx4*)&b3[n0q] * LOG2E
                          : (floatx4){0.f, 0.f, 0.f, 0.f};
    }
    {
        const bf16_t* W3b = W3P + (3 * w) * (KS_H * 512) + lane * 8;
        const bf16_t* Wqb = W3P + 12 * (KS_H * 512) + lane * 8;
        const bf16_t* Hb  = Hf + lane * 8;
        const bf16_t* Hq  = Hf + w * (KS_H * 512) + lane * 8;   // et = w fragment
        #pragma unroll 2
        for (int ks = 0; ks < KS_H; ks++) {
            bf16x8 hb0 = *(const bf16x8*)(Hb + ks * 512);
            bf16x8 hb1 = *(const bf16x8*)(Hb + ks * 512 + KS_H * 512);
            bf16x8 hb2 = *(const bf16x8*)(Hb + ks * 512 + 2 * KS_H * 512);
            bf16x8 hb3 = *(const bf16x8*)(Hb + ks * 512 + 3 * KS_H * 512);
            bf16x8 wq = *(const bf16x8*)(Wqb + ks * 512);
            bf16x8 hq = *(const bf16x8*)(Hq + ks * 512);
            __builtin_amdgcn_s_setprio(1);
            #pragma unroll
            for (int t = 0; t < 3; t++) {
                bf16x8 wf = *(const bf16x8*)(W3b + t * (KS_H * 512) + ks * 512);
                a3[t][0] = mfma16(wf, hb0, a3[t][0]);
                a3[t][1] = mfma16(wf, hb1, a3[t][1]);
                a3[t][2] = mfma16(wf, hb2, a3[t][2]);
                a3[t][3] = mfma16(wf, hb3, a3[t][3]);
            }
            aq = mfma16(wq, hq, aq);
            __builtin_amdgcn_s_setprio(0);
        }
    }
    // KL: mu -> sm += v*v; logvar (log2e units) -> se += exp2(v'), sv' += v',
    // cnt += group size. total = 0.5*(sm + se - ln2*sv' - cnt).
    float sm = 0.f, se = 0.f, svp = 0.f, cnt = 0.f;
    #pragma unroll
    for (int t = 0; t < 3; t++) {
        int n0 = (3 * w + t) * 16 + 4 * q;
        if (n0 < MSG) {                           // 4-runs never straddle 100
            #pragma unroll
            for (int e = 0; e < 4; e++)
                #pragma unroll
                for (int r = 0; r < 4; r++) {
                    float v = a3[t][e][r];
                    sm += v * v;
                }
        } else {
            #pragma unroll
            for (int e = 0; e < 4; e++)
                #pragma unroll
                for (int r = 0; r < 4; r++) {
                    float v = a3[t][e][r];
                    se += __builtin_exp2f(v);
                    svp += v;
                }
            cnt += 16.f;
        }
    }
    if (n0q < OUTC) {
        #pragma unroll
        for (int r = 0; r < 4; r++) {
            float v = aq[r];
            se += __builtin_exp2f(v);
            svp += v;
        }
        cnt += 4.f;
    }
    float s = sm + se - svp * LN2 - cnt;
    #pragma unroll
    for (int off = 32; off; off >>= 1) s += __shfl_down(s, off);
    if (lane == 0) red[w] = s;
    __syncthreads();
    if (tid == 0)
        part[blockIdx.x] = red[0] + red[1] + red[2] + red[3];   // plain store
}

extern "C" void kernel_launch(void* const* d_in, const int* in_sizes, int n_in,
                              void* d_out, int out_size, void* d_ws, size_t ws_size,
                              hipStream_t stream) {
    const float* x      = (const float*)d_in[0];
    const int*   ei     = (const int*)d_in[1];
    const float* y      = (const float*)d_in[2];
    const float* target = (const float*)d_in[3];
    const float* W1     = (const float*)d_in[4];
    const float* b1     = (const float*)d_in[5];
    const float* W2     = (const float*)d_in[6];
    const float* b2     = (const float*)d_in[7];
    const float* W3     = (const float*)d_in[8];
    const float* b3     = (const float*)d_in[9];
    float* out = (float*)d_out;

    bf16_t* W1P = (bf16_t*)d_ws;
    bf16_t* W2P = W1P + NT_H * 512;
    bf16_t* W3P = W2P + NT_H * KS_H * 512;
    float*  part = (float*)(W3P + NT_M * KS_H * 512);

    hipMemsetAsync(d_out, 0, sizeof(float), stream);
    prep_kernel<<<PREP_BLOCKS + LOSS_BLOCKS, 256, 0, stream>>>(
        W1, W2, W3, W1P, W2P, W3P, y, target, out);
    mlp_kernel<<<N_EDGES / MT, 256, 0, stream>>>(x, ei, W1P, W2P, W3P, b1, b2, b3, part);
    reduce_kernel<<<RED_BLOCKS, 256, 0, stream>>>(part, out);
}

// Round 8
// 405.278 us; speedup vs baseline: 2.2453x; 1.1344x over previous
//
#include <hip/hip_runtime.h>

#define N_NODES 100000
#define N_EDGES 1000000
#define D_FEAT  6
#define HIDDEN  300
#define HID_P   320          // padded hidden (multiple of 32)
#define MSG     100
#define OUTC    200          // 2*MSG
#define OUTC_P  208
#define MT      64           // edges per block
#define NT_H    (HID_P/16)   // 20 feature tiles for hidden layers
#define NT_M    13           // 13 feature tiles for messages (tile 12 partial)
#define KS_H    (HID_P/32)   // 10 k-steps of 32
#define NPART   (N_EDGES/MT) // 15625 per-block partials
#define LOG2E   1.44269504f
#define LN2     0.69314718f

typedef __bf16 bf16_t;
typedef __bf16 bf16x8 __attribute__((ext_vector_type(8)));
typedef __bf16 bf16x4 __attribute__((ext_vector_type(4)));
typedef __bf16 bf16x2 __attribute__((ext_vector_type(2)));
typedef float  floatx4 __attribute__((ext_vector_type(4)));

// ---------------- prep (weight pack) + base MAE loss, merged --------------------
// B-frag order pack: chunk of 512 el = one (ft,ks) fragment:
// el = ((ft*KS+ks)*64+lane)*8+j, element = W[k][n], n = ft*16+(lane&15),
// k = ks*32+(lane>>4)*8+j, zero-padded. W3 logvar cols (n>=MSG) pre-scaled by
// log2(e) so KL's exp is a bare v_exp_f32 (exp2).
#define PREP_BLOCKS 700
#define LOSS_BLOCKS 200
__global__ void prep_kernel(const float* __restrict__ W1, const float* __restrict__ W2,
                            const float* __restrict__ W3, bf16_t* __restrict__ W1P,
                            bf16_t* __restrict__ W2P, bf16_t* __restrict__ W3P,
                            const float* __restrict__ y, const float* __restrict__ t,
                            float* __restrict__ out) {
    if (blockIdx.x >= PREP_BLOCKS) {
        float s = 0.f;
        for (int i = (blockIdx.x - PREP_BLOCKS) * blockDim.x + threadIdx.x;
             i < N_NODES * 2; i += LOSS_BLOCKS * blockDim.x)
            s += fabsf(y[i] - t[i]);
        #pragma unroll
        for (int off = 32; off; off >>= 1) s += __shfl_down(s, off);
        __shared__ float red[4];
        if ((threadIdx.x & 63) == 0) red[threadIdx.x >> 6] = s;
        __syncthreads();
        if (threadIdx.x == 0)
            atomicAdd(out, (red[0] + red[1] + red[2] + red[3]) * (1.0f / N_NODES));
        return;
    }
    const int n1 = NT_H * 512;
    const int n2 = NT_H * KS_H * 512;
    const int n3 = NT_M * KS_H * 512;
    const int total = n1 + n2 + n3;
    for (int id = blockIdx.x * blockDim.x + threadIdx.x; id < total;
         id += PREP_BLOCKS * blockDim.x) {
        if (id < n1) {
            int nt = id >> 9, rem = id & 511, lane = rem >> 3, j = rem & 7;
            int n = nt * 16 + (lane & 15), k = (lane >> 4) * 8 + j;
            float v = (n < HIDDEN && k < 2 * D_FEAT) ? W1[k * HIDDEN + n] : 0.f;
            W1P[id] = (bf16_t)v;
        } else if (id < n1 + n2) {
            int r = id - n1;
            int chunk = r >> 9, rem = r & 511, lane = rem >> 3, j = rem & 7;
            int ks = chunk % KS_H, nt = chunk / KS_H;
            int n = nt * 16 + (lane & 15), k = ks * 32 + (lane >> 4) * 8 + j;
            float v = (n < HIDDEN && k < HIDDEN) ? W2[k * HIDDEN + n] : 0.f;
            W2P[r] = (bf16_t)v;
        } else {
            int r = id - n1 - n2;
            int chunk = r >> 9, rem = r & 511, lane = rem >> 3, j = rem & 7;
            int ks = chunk % KS_H, nt = chunk / KS_H;
            int n = nt * 16 + (lane & 15), k = ks * 32 + (lane >> 4) * 8 + j;
            float v = (n < OUTC && k < HIDDEN) ? W3[k * OUTC + n] : 0.f;
            if (n >= MSG) v *= LOG2E;            // logvar columns pre-scaled
            W3P[r] = (bf16_t)v;
        }
    }
}

// ---------------- final reduce: sum per-block KL partials into out -------------
#define RED_BLOCKS 64
__global__ void reduce_kernel(const float* __restrict__ part, float* __restrict__ out) {
    float s = 0.f;
    for (int i = blockIdx.x * blockDim.x + threadIdx.x; i < NPART;
         i += RED_BLOCKS * blockDim.x)
        s += part[i];
    #pragma unroll
    for (int off = 32; off; off >>= 1) s += __shfl_down(s, off);
    __shared__ float red[4];
    if ((threadIdx.x & 63) == 0) red[threadIdx.x >> 6] = s;
    __syncthreads();
    if (threadIdx.x == 0)
        atomicAdd(out, (red[0] + red[1] + red[2] + red[3]) * (0.5f / N_EDGES));
}

static __device__ __forceinline__ floatx4 mfma16(bf16x8 a, bf16x8 b, floatx4 c) {
    return __builtin_amdgcn_mfma_f32_16x16x32_bf16(a, b, c, 0, 0, 0);
}

// GEMM phase, 4-wave decomposition: wave w owns nts {5w..5w+4} x all 4 edge
// tiles = 20 jobs/wave, exactly balanced. BIAS RIDES IN C. No setprio: R7
// showed the R4-era setprio/gather combo cost ~25% (uniform MfmaUtil stretch);
// T5 is null-to-negative on lockstep GEMM loops (catalog m190).
template<int KSN, int SE>
__device__ __forceinline__ void gemm5x4(
    const bf16_t* __restrict__ Wbase0,     // W pack + (5w)*KSN*512
    const bf16_t* __restrict__ Hsrc, int lane,
    const floatx4 (&binit)[5], floatx4 (&acc)[5][4]) {
    #pragma unroll
    for (int i = 0; i < 5; i++)
        #pragma unroll
        for (int e = 0; e < 4; e++) acc[i][e] = binit[i];
    const bf16_t* Wb = Wbase0 + lane * 8;
    const bf16_t* Hb = Hsrc + lane * 8;
    #pragma unroll 2
    for (int ks = 0; ks < KSN; ks++) {
        bf16x8 hb0 = *(const bf16x8*)(Hb + ks * 512);
        bf16x8 hb1 = *(const bf16x8*)(Hb + ks * 512 + SE);
        bf16x8 hb2 = *(const bf16x8*)(Hb + ks * 512 + 2 * SE);
        bf16x8 hb3 = *(const bf16x8*)(Hb + ks * 512 + 3 * SE);
        #pragma unroll
        for (int i = 0; i < 5; i++) {
            bf16x8 wf = *(const bf16x8*)(Wb + i * (KSN * 512) + ks * 512);
            acc[i][0] = mfma16(wf, hb0, acc[i][0]);
            acc[i][1] = mfma16(wf, hb1, acc[i][1]);
            acc[i][2] = mfma16(wf, hb2, acc[i][2]);
            acc[i][3] = mfma16(wf, hb3, acc[i][3]);
        }
    }
}

// Epilogue: relu + pack to bf16 (bias already in C), write in B-frag order.
// C/D layout: n(edge)=lane&15, m(feat)=(lane>>4)*4+reg  (verified, absmax 0).
__device__ __forceinline__ void epi5(
    bf16_t* __restrict__ Hf, int w, int q, int l16, const floatx4 (&acc)[5][4]) {
    #pragma unroll
    for (int i = 0; i < 5; i++) {
        int n0 = (5 * w + i) * 16 + 4 * q;
        int ks = n0 >> 5, lp = l16 + 16 * ((n0 >> 3) & 3), j0 = n0 & 7;
        #pragma unroll
        for (int e = 0; e < 4; e++) {
            bf16x4 pk;
            #pragma unroll
            for (int r = 0; r < 4; r++)
                pk[r] = (bf16_t)fmaxf(acc[i][e][r], 0.f);
            *(bf16x4*)&Hf[((e * KS_H + ks) * 64 + lp) * 8 + j0] = pk;
        }
    }
}

// ---------------- fused edge MLP + KL ------------------------------------------
// OPERAND SWAP: D = mfma(A=W_frag, B=H_frag) -> D rows = features, cols = edges.
// H in LDS in exact B-fragment order Hf[e][ks][lane][8]. Gather is the R3
// cooperative LDS-staged version (128 threads, 1 barrier) — the R4 direct-
// global per-wave gather was part of a ~25% regression. NO same-address
// atomics (R5-R7: they serialize ~13ns each at the coherence point;
// WRITE_SIZE = 32B x atomic count): per-block partial -> store -> reduce.
__global__ __launch_bounds__(256, 3) void mlp_kernel(
    const float* __restrict__ x, const int* __restrict__ ei,
    const bf16_t* __restrict__ W1P, const bf16_t* __restrict__ W2P,
    const bf16_t* __restrict__ W3P,
    const float* __restrict__ b1, const float* __restrict__ b2,
    const float* __restrict__ b3, float* __restrict__ part) {
    __shared__ __align__(16) bf16_t A1f[4 * 64 * 8];          // 4 KB, frag order
    __shared__ __align__(16) bf16_t Hf[4 * KS_H * 64 * 8];    // 40 KB, frag order
    __shared__ float red[4];

    const int tid  = threadIdx.x;
    const int w    = tid >> 6, lane = tid & 63;
    const int q    = lane >> 4, l16 = lane & 15;
    const long e0 = (long)blockIdx.x * MT;

    // ---- preload W1 fragments + b1/b2 C-init vectors (hide L2 behind gather) --
    bf16x8 wf1[5];
    floatx4 bv1[5], bv2[5];
    #pragma unroll
    for (int i = 0; i < 5; i++) {
        wf1[i] = *(const bf16x8*)&W1P[((5 * w + i) * 64 + lane) * 8];
        int n0 = (5 * w + i) * 16 + 4 * q;
        bv1[i] = (n0 < HIDDEN) ? *(const floatx4*)&b1[n0] : (floatx4){0.f, 0.f, 0.f, 0.f};
        bv2[i] = (n0 < HIDDEN) ? *(const floatx4*)&b2[n0] : (floatx4){0.f, 0.f, 0.f, 0.f};
    }

    // gather: edge features -> A1f fragment order, zero-padding embedded;
    // all writes disjoint, single barrier. elem(lane',j) = feat k of edge
    // (et*16 + (lane'&15)), k = (lane'>>4)*8 + j.
    if (tid < 2 * MT) {
        int m = tid >> 1, side = tid & 1;
        int node = ei[(long)side * N_EDGES + e0 + m];
        const float2* xr = (const float2*)(x + (long)node * D_FEAT);
        float2 v0 = xr[0], v1 = xr[1], v2 = xr[2];
        int et = m >> 4, ml = m & 15;
        bf16_t* Ab = &A1f[(et * 64 + ml) * 8];
        if (side == 0) {                       // k = 0..5 -> row ml, j 0..5
            bf16x4 lo = {(bf16_t)v0.x, (bf16_t)v0.y, (bf16_t)v1.x, (bf16_t)v1.y};
            *(bf16x4*)&Ab[0] = lo;
            bf16x2 mid = {(bf16_t)v2.x, (bf16_t)v2.y};
            *(bf16x2*)&Ab[4] = mid;
        } else {                               // k = 6,7 -> row ml; k = 8..11 -> row ml+16 (+zeros)
            bf16x2 hi2 = {(bf16_t)v0.x, (bf16_t)v0.y};
            *(bf16x2*)&Ab[6] = hi2;
            bf16x8 top = {(bf16_t)v1.x, (bf16_t)v1.y, (bf16_t)v2.x, (bf16_t)v2.y,
                          (bf16_t)0.f, (bf16_t)0.f, (bf16_t)0.f, (bf16_t)0.f};
            *(bf16x8*)&A1f[(et * 64 + ml + 16) * 8] = top;
        }
    } else {                                   // zero rows lane>=32 (k 16..31)
        int idx = tid - 128;                   // 0..127
        int et = idx >> 5, lr = 32 + (idx & 31);
        bf16x8 z = {};
        *(bf16x8*)&A1f[(et * 64 + lr) * 8] = z;
    }
    __syncthreads();

    floatx4 acc[5][4];

    // ---- GEMM1: h1 = relu(e @ W1 + b1), K=32 (one step), bias in C ----
    {
        bf16x8 hb0 = *(const bf16x8*)&A1f[lane * 8];
        bf16x8 hb1 = *(const bf16x8*)&A1f[(64 + lane) * 8];
        bf16x8 hb2 = *(const bf16x8*)&A1f[(128 + lane) * 8];
        bf16x8 hb3 = *(const bf16x8*)&A1f[(192 + lane) * 8];
        #pragma unroll
        for (int i = 0; i < 5; i++) {
            acc[i][0] = mfma16(wf1[i], hb0, bv1[i]);
            acc[i][1] = mfma16(wf1[i], hb1, bv1[i]);
            acc[i][2] = mfma16(wf1[i], hb2, bv1[i]);
            acc[i][3] = mfma16(wf1[i], hb3, bv1[i]);
        }
    }
    epi5(Hf, w, q, l16, acc);
    __syncthreads();

    // ---- GEMM2: h2 = relu(h1 @ W2 + b2), K=320, bias in C ----
    gemm5x4<KS_H, KS_H * 512>(W2P + (5 * w) * (KS_H * 512), Hf, lane, bv2, acc);
    __syncthreads();   // all Hf(h1) reads done before overwrite
    epi5(Hf, w, q, l16, acc);
    __syncthreads();

    // ---- GEMM3: messages = h2 @ W3(+log2e-scaled lv) + b3 (bias in C), KL ----
    floatx4 a3[3][4], aq;
    const int n0q = 192 + 4 * q;                  // tile 12, logvar only
    {
        #pragma unroll
        for (int t = 0; t < 3; t++) {
            int n0 = (3 * w + t) * 16 + 4 * q;    // 0..191, always valid
            floatx4 bv = *(const floatx4*)&b3[n0];
            if (n0 >= MSG) bv = bv * LOG2E;       // logvar bias in log2e units
            #pragma unroll
            for (int e = 0; e < 4; e++) a3[t][e] = bv;
        }
        aq = (n0q < OUTC) ? *(const floatx4*)&b3[n0q] * LOG2E
                          : (floatx4){0.f, 0.f, 0.f, 0.f};
    }
    {
        const bf16_t* W3b = W3P + (3 * w) * (KS_H * 512) + lane * 8;
        const bf16_t* Wqb = W3P + 12 * (KS_H * 512) + lane * 8;
        const bf16_t* Hb  = Hf + lane * 8;
        const bf16_t* Hq  = Hf + w * (KS_H * 512) + lane * 8;   // et = w fragment
        #pragma unroll 2
        for (int ks = 0; ks < KS_H; ks++) {
            bf16x8 hb0 = *(const bf16x8*)(Hb + ks * 512);
            bf16x8 hb1 = *(const bf16x8*)(Hb + ks * 512 + KS_H * 512);
            bf16x8 hb2 = *(const bf16x8*)(Hb + ks * 512 + 2 * KS_H * 512);
            bf16x8 hb3 = *(const bf16x8*)(Hb + ks * 512 + 3 * KS_H * 512);
            #pragma unroll
            for (int t = 0; t < 3; t++) {
                bf16x8 wf = *(const bf16x8*)(W3b + t * (KS_H * 512) + ks * 512);
                a3[t][0] = mfma16(wf, hb0, a3[t][0]);
                a3[t][1] = mfma16(wf, hb1, a3[t][1]);
                a3[t][2] = mfma16(wf, hb2, a3[t][2]);
                a3[t][3] = mfma16(wf, hb3, a3[t][3]);
            }
            bf16x8 wq = *(const bf16x8*)(Wqb + ks * 512);
            bf16x8 hq = *(const bf16x8*)(Hq + ks * 512);
            aq = mfma16(wq, hq, aq);
        }
    }
    // KL: mu -> sm += v*v; logvar (log2e units) -> se += exp2(v'), sv' += v',
    // cnt += group size. total = 0.5*(sm + se - ln2*sv' - cnt).
    float sm = 0.f, se = 0.f, svp = 0.f, cnt = 0.f;
    #pragma unroll
    for (int t = 0; t < 3; t++) {
        int n0 = (3 * w + t) * 16 + 4 * q;
        if (n0 < MSG) {                           // 4-runs never straddle 100
            #pragma unroll
            for (int e = 0; e < 4; e++)
                #pragma unroll
                for (int r = 0; r < 4; r++) {
                    float v = a3[t][e][r];
                    sm += v * v;
                }
        } else {
            #pragma unroll
            for (int e = 0; e < 4; e++)
                #pragma unroll
                for (int r = 0; r < 4; r++) {
                    float v = a3[t][e][r];
                    se += __builtin_exp2f(v);
                    svp += v;
                }
            cnt += 16.f;
        }
    }
    if (n0q < OUTC) {
        #pragma unroll
        for (int r = 0; r < 4; r++) {
            float v = aq[r];
            se += __builtin_exp2f(v);
            svp += v;
        }
        cnt += 4.f;
    }
    float s = sm + se - svp * LN2 - cnt;
    #pragma unroll
    for (int off = 32; off; off >>= 1) s += __shfl_down(s, off);
    if (lane == 0) red[w] = s;
    __syncthreads();
    if (tid == 0)
        part[blockIdx.x] = red[0] + red[1] + red[2] + red[3];   // plain store
}

extern "C" void kernel_launch(void* const* d_in, const int* in_sizes, int n_in,
                              void* d_out, int out_size, void* d_ws, size_t ws_size,
                              hipStream_t stream) {
    const float* x      = (const float*)d_in[0];
    const int*   ei     = (const int*)d_in[1];
    const float* y      = (const float*)d_in[2];
    const float* target = (const float*)d_in[3];
    const float* W1     = (const float*)d_in[4];
    const float* b1     = (const float*)d_in[5];
    const float* W2     = (const float*)d_in[6];
    const float* b2     = (const float*)d_in[7];
    const float* W3     = (const float*)d_in[8];
    const float* b3     = (const float*)d_in[9];
    float* out = (float*)d_out;

    bf16_t* W1P = (bf16_t*)d_ws;
    bf16_t* W2P = W1P + NT_H * 512;
    bf16_t* W3P = W2P + NT_H * KS_H * 512;
    float*  part = (float*)(W3P + NT_M * KS_H * 512);

    hipMemsetAsync(d_out, 0, sizeof(float), stream);
    prep_kernel<<<PREP_BLOCKS + LOSS_BLOCKS, 256, 0, stream>>>(
        W1, W2, W3, W1P, W2P, W3P, y, target, out);
    mlp_kernel<<<N_EDGES / MT, 256, 0, stream>>>(x, ei, W1P, W2P, W3P, b1, b2, b3, part);
    reduce_kernel<<<RED_BLOCKS, 256, 0, stream>>>(part, out);
}